// Round 3
// baseline (1246.826 us; speedup 1.0000x reference)
//
#include <hip/hip_runtime.h>

#define THREADS 256
#define SPB 4   // one sample per wave64

// fast reciprocal (v_rcp_f32, ~1 ulp) — IEEE divide costs ~10 VALU ops without fast-math
__device__ __forceinline__ float frcp(float x){ return __builtin_amdgcn_rcpf(x); }
__device__ __forceinline__ float fsig(float x){ return frcp(1.0f + __expf(-x)); }
// tanh = 1 - 2/(e^{2x}+1): e->inf gives 1, e->0 gives -1; no clamp needed
__device__ __forceinline__ float ftanh(float x){
    float e = __expf(2.0f * x);
    return fmaf(-2.0f, frcp(e + 1.0f), 1.0f);
}
// NaN-PROPAGATING leaky relu
__device__ __forceinline__ float lrelu(float x){ return x > 0.0f ? x : 0.01f * x; }

__global__ void diag_kernel(float* outp, float code){ outp[0] = code; }

// 5-step LSTM recurrence, full-wave layout: lane owns (j = lane&31, gate-pair p = lane>>5).
// p=0 -> gates {i,f} (rows j, 32+j), p=1 -> gates {g,o} (rows 64+j, 96+j).
// wh register-resident (64 floats/lane). h_t written to hout[t*32+j] (lanes<32) and
// broadcast-read as float4 at step t+1 (same wave -> compiler lgkmcnt orders it).
// s1/s2 accumulate LN sums over the wave (each (t,j) counted twice -> caller scales /320).
__device__ __forceinline__ void lstm_rec_fw(const float* __restrict__ whh,
                                            const float (&acc)[5][2],
                                            float* __restrict__ hout,
                                            int lane, int j, int p,
                                            float& s1o, float& s2o)
{
    float wh0[32], wh1[32];
    {
        const float* r0 = whh + (size_t)((2*p + 0)*32 + j)*32;
        const float* r1 = whh + (size_t)((2*p + 1)*32 + j)*32;
        #pragma unroll
        for (int q = 0; q < 8; ++q){
            float4 a = *(const float4*)(r0 + q*4);
            wh0[q*4+0]=a.x; wh0[q*4+1]=a.y; wh0[q*4+2]=a.z; wh0[q*4+3]=a.w;
            float4 b = *(const float4*)(r1 + q*4);
            wh1[q*4+0]=b.x; wh1[q*4+1]=b.y; wh1[q*4+2]=b.z; wh1[q*4+3]=b.w;
        }
    }
    const bool lo = (lane < 32);
    const float sc  = p ? 2.0f : -1.0f;   // see below: fold sign into scale
    float h = 0.0f, c = 0.0f, s1 = 0.0f, s2 = 0.0f;
    #pragma unroll
    for (int t = 0; t < 5; ++t){
        float q0a = acc[t][0], q1 = acc[t][1], q0b = 0.0f, q1b = 0.0f;
        if (t > 0){
            const float* hp = hout + (t-1)*32;
            #pragma unroll
            for (int k0 = 0; k0 < 32; k0 += 8){
                float4 ha = *(const float4*)(hp + k0);       // broadcast, conflict-free
                float4 hc = *(const float4*)(hp + k0 + 4);
                q0a = fmaf(wh0[k0+0], ha.x, q0a);  q1  = fmaf(wh1[k0+0], ha.x, q1);
                q0a = fmaf(wh0[k0+1], ha.y, q0a);  q1  = fmaf(wh1[k0+1], ha.y, q1);
                q0a = fmaf(wh0[k0+2], ha.z, q0a);  q1  = fmaf(wh1[k0+2], ha.z, q1);
                q0a = fmaf(wh0[k0+3], ha.w, q0a);  q1  = fmaf(wh1[k0+3], ha.w, q1);
                q0b = fmaf(wh0[k0+4], hc.x, q0b);  q1b = fmaf(wh1[k0+4], hc.x, q1b);
                q0b = fmaf(wh0[k0+5], hc.y, q0b);  q1b = fmaf(wh1[k0+5], hc.y, q1b);
                q0b = fmaf(wh0[k0+6], hc.z, q0b);  q1b = fmaf(wh1[k0+6], hc.z, q1b);
                q0b = fmaf(wh0[k0+7], hc.w, q0b);  q1b = fmaf(wh1[k0+7], hc.w, q1b);
            }
        }
        float q0 = q0a + q0b;
        float qf = q1 + q1b;
        // p=0: v0 = sigmoid(q0); p=1: v0 = tanh(q0) = 2*sigmoid(2*q0) - 1
        // unified: p=0: sc=-1 -> v0 = -sigmoid(-(-q0))?  use explicit forms instead:
        float v0;
        if (p == 0) v0 = fsig(q0);
        else        v0 = fmaf(2.0f, fsig(2.0f*q0), -1.0f);
        float v1 = fsig(qf);                       // f (p=0) or o (p=1)
        float x0 = __shfl_xor(v0, 32, 64);
        float x1 = __shfl_xor(v1, 32, 64);
        float iv = p ? x0 : v0;
        float gv = p ? v0 : x0;
        float fv = p ? x1 : v1;
        float ov = p ? v1 : x1;
        c = fmaf(fv, c, iv * gv);
        h = ov * ftanh(c);
        s1 += h; s2 = fmaf(h, h, s2);
        if (lo) hout[t*32 + j] = h;
    }
    (void)sc;
    s1o = s1; s2o = s2;
}

// NOTE (empirical, R0-R2): effective VGPR budget/SIMD on this toolchain is 256:
// waves/SIMD = floor(256/VGPR). R1's (256,4) clamped to 64 VGPR -> scratch spill
// catastrophe. Keep (256,1) and reduce NATURAL pressure instead (this round: 2 gates/lane).
__global__ __launch_bounds__(THREADS, 1)
void reslstm_kernel(const float* __restrict__ data,
                    const float* __restrict__ wih0, const float* __restrict__ whh0,
                    const float* __restrict__ bih0, const float* __restrict__ bhh0,
                    const float* __restrict__ g0p,  const float* __restrict__ be0p,
                    const float* __restrict__ wih1, const float* __restrict__ whh1,
                    const float* __restrict__ bih1, const float* __restrict__ bhh1,
                    const float* __restrict__ g1p,  const float* __restrict__ be1p,
                    const float* __restrict__ dwp,  const float* __restrict__ dbp,
                    float* __restrict__ outp, int Btot)
{
    // xs: [s][t][64] input (pad n=62,63 = 0); after phase A it is reused as
    // layer-1 h scratch [s][160] (per-wave private region -> no barrier needed).
    __shared__ __attribute__((aligned(16))) float xs[SPB*320];
    // wbuf phase A: wih0 [128][68]; phase B: wih1 [128][36] (reuse)
    __shared__ __attribute__((aligned(16))) float wbuf[128*68];
    __shared__ __attribute__((aligned(16))) float out0s[SPB*160];
    __shared__ float bias0s[128], bias1s[128];
    __shared__ float g0s[160], be0s[160], g1s[160], be1s[160];
    __shared__ float dws[480];
    __shared__ float dbs[3];

    const int tid = threadIdx.x;
    const int b0  = blockIdx.x * SPB;
    const int nsamp = (Btot - b0 < SPB) ? (Btot - b0) : SPB;

    // ---------------- stage (coalesced fp32 global -> LDS) ----------------
    {
        const float* dat = data + (size_t)b0 * 310;   // sample chunk: idx = n*5 + t
        for (int i = tid; i < nsamp*310; i += THREADS){
            int s = i / 310, r = i - s*310;
            int n = r / 5,   t = r - n*5;
            xs[s*320 + t*64 + n] = dat[i];
        }
        for (int i = tid; i < SPB*10; i += THREADS){          // zero pad n=62,63
            int s = i / 10, q = i - s*10;
            xs[s*320 + (q>>1)*64 + 62 + (q&1)] = 0.0f;
        }
        for (int i = tid; i < 128*62; i += THREADS){
            int row = i / 62, n = i - row*62;
            wbuf[row*68 + n] = wih0[i];
        }
        for (int i = tid; i < 128*6; i += THREADS){           // zero pad n=62..67
            int row = i / 6, n = i - row*6;
            wbuf[row*68 + 62 + n] = 0.0f;
        }
        if (tid < 128)  bias0s[tid] = bih0[tid] + bhh0[tid];
        else            { int q = tid - 128; bias1s[q] = bih1[q] + bhh1[q]; }
        if (tid < 160){
            g0s[tid] = g0p[tid];  be0s[tid] = be0p[tid];
            g1s[tid] = g1p[tid];  be1s[tid] = be1p[tid];
        }
        for (int i = tid; i < 480; i += THREADS) dws[i] = dwp[i];
        if (tid < 3) dbs[tid] = dbp[tid];
    }
    __syncthreads();

    const int lane = tid & 63;
    const int j    = lane & 31;   // hidden unit
    const int p    = lane >> 5;   // gate-pair: 0 -> {i,f}, 1 -> {g,o}
    const int s    = tid >> 6;    // wave = sample-in-block
    const bool lo  = (lane < 32);

    float* xsc  = xs    + s*320;  // input, later layer-1 h scratch
    float* o0l  = out0s + s*160;

    // ---------------- phase A: xg0 = x @ W_ih0^T + biases ----------------
    float acc[5][2];
    {
        float bv0 = bias0s[(2*p + 0)*32 + j];
        float bv1 = bias0s[(2*p + 1)*32 + j];
        #pragma unroll
        for (int t = 0; t < 5; ++t){ acc[t][0] = bv0; acc[t][1] = bv1; }
    }
    {
        const float* wp = wbuf + (size_t)(64*p + j)*68;
        #pragma unroll 4
        for (int n0 = 0; n0 < 64; n0 += 4){
            float4 w0 = *(const float4*)(wp + n0);            // row (2p)*32+j
            float4 w1 = *(const float4*)(wp + 32*68 + n0);    // row (2p+1)*32+j
            #pragma unroll
            for (int t = 0; t < 5; ++t){
                float4 xv = *(const float4*)(xsc + t*64 + n0);  // wave-broadcast
                acc[t][0] = fmaf(w0.x, xv.x, fmaf(w0.y, xv.y, fmaf(w0.z, xv.z, fmaf(w0.w, xv.w, acc[t][0]))));
                acc[t][1] = fmaf(w1.x, xv.x, fmaf(w1.y, xv.y, fmaf(w1.z, xv.z, fmaf(w1.w, xv.w, acc[t][1]))));
            }
        }
    }

    // ---------------- layer 0 recurrence + LN + LeakyReLU ----------------
    {
        float s1, s2;
        lstm_rec_fw(whh0, acc, o0l, lane, j, p, s1, s2);
        #pragma unroll
        for (int m = 1; m <= 32; m <<= 1){
            s1 += __shfl_xor(s1, m, 64);
            s2 += __shfl_xor(s2, m, 64);
        }
        float mu   = s1 * (1.0f/320.0f);            // 64 lanes double-count 160 values
        float var  = s2 * (1.0f/320.0f) - mu*mu;
        float rstd = rsqrtf(var + 1e-5f);
        #pragma unroll
        for (int t = 0; t < 5; ++t){
            float v = o0l[t*32 + j];                 // 2-lane same-addr broadcast
            float y = lrelu(fmaf((v - mu)*rstd, g0s[t*32 + j], be0s[t*32 + j]));
            if (lo) o0l[t*32 + j] = y;
        }
    }

    __syncthreads();
    // ---------------- restage wih1 into wbuf [128][36] ----------------
    for (int i = tid; i < 128*32; i += THREADS){
        int row = i >> 5, k = i & 31;
        wbuf[row*36 + k] = wih1[i];
    }
    for (int i = tid; i < 128*4; i += THREADS){
        int row = i >> 2;
        wbuf[row*36 + 32 + (i & 3)] = 0.0f;
    }
    __syncthreads();

    // ---------------- phase B: xg1 = out0 @ W_ih1^T + biases ----------------
    {
        float bv0 = bias1s[(2*p + 0)*32 + j];
        float bv1 = bias1s[(2*p + 1)*32 + j];
        #pragma unroll
        for (int t = 0; t < 5; ++t){ acc[t][0] = bv0; acc[t][1] = bv1; }
    }
    {
        const float* wp1 = wbuf + (size_t)(64*p + j)*36;
        #pragma unroll 4
        for (int k0 = 0; k0 < 32; k0 += 4){
            float4 w0 = *(const float4*)(wp1 + k0);
            float4 w1 = *(const float4*)(wp1 + 32*36 + k0);
            #pragma unroll
            for (int t = 0; t < 5; ++t){
                float4 ov = *(const float4*)(o0l + t*32 + k0);  // wave-broadcast
                acc[t][0] = fmaf(w0.x, ov.x, fmaf(w0.y, ov.y, fmaf(w0.z, ov.z, fmaf(w0.w, ov.w, acc[t][0]))));
                acc[t][1] = fmaf(w1.x, ov.x, fmaf(w1.y, ov.y, fmaf(w1.z, ov.z, fmaf(w1.w, ov.w, acc[t][1]))));
            }
        }
    }

    // ---------------- layer 1 recurrence + LN + residual + head ----------------
    float p0 = 0.0f, p1 = 0.0f, p2 = 0.0f;
    {
        float s1, s2;
        lstm_rec_fw(whh1, acc, xsc, lane, j, p, s1, s2);   // xs reused as h scratch
        #pragma unroll
        for (int m = 1; m <= 32; m <<= 1){
            s1 += __shfl_xor(s1, m, 64);
            s2 += __shfl_xor(s2, m, 64);
        }
        float mu   = s1 * (1.0f/320.0f);
        float var  = s2 * (1.0f/320.0f) - mu*mu;
        float rstd = rsqrtf(var + 1e-5f);
        #pragma unroll
        for (int t = 0; t < 5; ++t){
            float v  = xsc[t*32 + j];
            float y  = lrelu(fmaf((v - mu)*rstd, g1s[t*32 + j], be1s[t*32 + j]));
            float o  = y + o0l[t*32 + j];            // residual
            p0 = fmaf(dws[      t*32 + j], o, p0);
            p1 = fmaf(dws[160 + t*32 + j], o, p1);
            p2 = fmaf(dws[320 + t*32 + j], o, p2);
        }
    }
    #pragma unroll
    for (int m = 1; m <= 32; m <<= 1){
        p0 += __shfl_xor(p0, m, 64);
        p1 += __shfl_xor(p1, m, 64);
        p2 += __shfl_xor(p2, m, 64);
    }
    // 64-lane reduce double-counts each j -> scale 0.5
    if (lane < 3 && s < nsamp){
        float v = (lane == 0) ? p0 : ((lane == 1) ? p1 : p2);
        v = lrelu(fmaf(0.5f, v, dbs[lane]));
        outp[(size_t)(b0 + s)*3 + lane] = v;
    }
}

extern "C" void kernel_launch(void* const* d_in, const int* in_sizes, int n_in,
                              void* d_out, int out_size, void* d_ws, size_t ws_size,
                              hipStream_t stream)
{
    (void)d_ws; (void)ws_size;

    const int B = out_size / 3;

    // Locate 'data' = largest input; infer the harness's input ordering from it.
    int idx_data = 0;
    for (int i = 1; i < n_in; ++i)
        if (in_sizes[i] > in_sizes[idx_data]) idx_data = i;

    // semantic slots (reference dict order):
    // 0 data,1 wih0,2 whh0,3 bih0,4 bhh0,5 g0,6 be0,7 wih1,8 whh1,9 bih1,
    // 10 bhh1,11 g1,12 be1,13 dw,14 db
    static const int dict_map[15]  = {0,1,2,3,4,5,6,7,8,9,10,11,12,13,14};
    // alphabetical key order fallback
    static const int alpha_map[15] = {6,13,11,2,0,9,4,14,12,3,1,10,5,8,7};
    static const int rev_map[15]   = {14,13,12,11,10,9,8,7,6,5,4,3,2,1,0};

    const int* map = dict_map;
    if (idx_data == 6)       map = alpha_map;
    else if (idx_data == 14) map = rev_map;

    long ds  = (long)in_sizes[idx_data];
    long ws0 = (long)in_sizes[map[1]];
    bool ok = (ds == (long)B*310 || ds == (long)B*620 || ds == (long)B*1240)
           && (ws0 == 7936 || ws0 == 15872 || ws0 == 31744);

    if (!ok || B <= 0){
        diag_kernel<<<1, 1, 0, stream>>>((float*)d_out, 100.0f + 10.0f*idx_data);
        return;
    }

    const float* P[15];
    for (int k = 0; k < 15; ++k) P[k] = (const float*)d_in[map[k]];

    const int nblocks = (B + SPB - 1) / SPB;
    reslstm_kernel<<<dim3(nblocks), dim3(THREADS), 0, stream>>>(
        P[0], P[1], P[2], P[3], P[4], P[5], P[6], P[7], P[8], P[9],
        P[10], P[11], P[12], P[13], P[14],
        (float*)d_out, B);
}